// Round 7
// baseline (256.466 us; speedup 1.0000x reference)
//
#include <hip/hip_runtime.h>

// DynamicConv2d: B=64, C=8, H=W=256, OUT_C=8, K=3, IN_FEAT=8
// out[b,oc,h,w] = sum_{ic,kh,kw} x[b,ic,h+kh-1,w+kw-1] *
//                 ( dot(dw[b,oc,:], Wg[ic*9+kh*3+kw,:]) + bg[ic*9+kh*3+kw] )
//
// Session log (conv-dispatch times):
//   R0: RPB=8 thread-per-col, 68 VGPR, occ 25.8%            -> 90.6 us
//   R2-R5: tilings w/ __launch_bounds__(..,8): 32-VGPR cap  -> 101-300 us
//          (allocator spilled inner loop -> scratch traffic masqueraded as
//           "write amplification": WRITE up to 686 MB vs 131 real)
//   R6: RPB=4, NO min-waves: 40 VGPR, occ 52%, WRITE=131MB  -> 88 us
//       ... same speed as R0 at 2x occupancy => NOT occupancy-bound.
//       VALUBusy 46% (FMA floor 31 us), HBM 2.7 of 6.3 TB/s => latency-bound:
//       per-ic serial {s_load wk -> x loads -> FMA} chain, waves convoy.
//   R7 (this): 2-deep software pipeline over ic — double-buffered x-row
//       registers (named A/B, ic unrolled by 2 for static indexing), next
//       ic's 18 loads issued BEFORE current ic's FMA block.
//   Rules learned: (1) __launch_bounds__ 2nd arg is a VGPR budget; over-ask
//   converts registers into scratch traffic (check WRITE_SIZE == 131072);
//   (2) plain stride-1 scalar stores write exactly output size; (3) shuffle
//   halos cost more than L1-hit neighbor loads.

#define HC   65536   // H*W
#define WW   256
#define RPB  4       // output rows per block; input rows per ic = RPB+2 = 6

// ---------------------------------------------------------------------------
// Kernel 1: materialize per-sample conv weights into d_ws with layout
//   kern[b][ic][kh][kw][oc]  (so conv reads 72 contiguous floats per (b,ic))
// ---------------------------------------------------------------------------
__global__ __launch_bounds__(576) void gen_kernels(
    const float* __restrict__ dw,   // (B, 8, 8)
    const float* __restrict__ Wg,   // (72, 8)
    const float* __restrict__ bg,   // (72,)
    float* __restrict__ kern)       // (B, 576)
{
    const int b = blockIdx.x;
    const int j = threadIdx.x;
    if (j >= 576) return;
    const int ic   = j / 72;
    const int rem  = j % 72;
    const int kh   = rem / 24;
    const int rem2 = rem % 24;
    const int kw   = rem2 / 8;
    const int oc   = rem2 % 8;
    const int o    = ic * 9 + kh * 3 + kw;   // lin output index

    const float* d = dw + b * 64 + oc * 8;
    const float* g = Wg + o * 8;
    float v = bg[o];
#pragma unroll
    for (int i = 0; i < 8; ++i) v = fmaf(d[i], g[i], v);
    kern[b * 576 + j] = v;
}

// ---------------------------------------------------------------------------
// Kernel 2: the conv, software-pipelined over ic.
// One block = one sample b x one 4-row tile, 256 threads = one thread per W
// column (stride-1 coalesced loads/stores — measured minimal traffic).
// Two named register buffers (Am/Ac/Ap and Bm/Bc/Bp, 18 floats each) hold
// the 6 input rows x {left,center,right} taps for the current / next ic.
// ic unrolled by 2 so every buffer index is compile-time (no scratch).
// ---------------------------------------------------------------------------

// Issue the 18 loads for channel (IC) into buffer (M,C,P). Per-lane edge
// guards on w; row guard is block-uniform.
#define LOADIC(IC, M, C, P)                                            \
    {                                                                  \
        const float* xch = xb + (IC) * HC;                             \
        _Pragma("unroll")                                              \
        for (int ri = 0; ri < RPB + 2; ++ri) {                         \
            const int row = h0 - 1 + ri;                               \
            M[ri] = 0.f; C[ri] = 0.f; P[ri] = 0.f;                     \
            if (row >= 0 && row < 256) {                               \
                const float* xr = xch + row * WW;                      \
                C[ri] = xr[w];                                         \
                M[ri] = (w > 0)   ? xr[w - 1] : 0.f;                   \
                P[ri] = (w < 255) ? xr[w + 1] : 0.f;                   \
            }                                                          \
        }                                                              \
    }

// Load 72 wave-uniform weights for channel (IC) into wk (SGPRs), then
// accumulate buffer (M,C,P) into acc.
#define COMPUTEIC(IC, M, C, P)                                         \
    {                                                                  \
        float wk[72];                                                  \
        const float* Kic = Kb + (IC) * 72;                             \
        _Pragma("unroll")                                              \
        for (int t = 0; t < 72; ++t) wk[t] = Kic[t];                   \
        _Pragma("unroll")                                              \
        for (int ri = 0; ri < RPB + 2; ++ri) {                         \
            _Pragma("unroll")                                          \
            for (int kh = 0; kh < 3; ++kh) {                           \
                const int ro = ri - kh;                                \
                if (ro < 0 || ro >= RPB) continue;                     \
                const float* wr = &wk[kh * 24];                        \
                _Pragma("unroll")                                      \
                for (int oc = 0; oc < 8; ++oc) {                       \
                    float a = acc[ro][oc];                             \
                    a = fmaf(M[ri], wr[0 * 8 + oc], a);                \
                    a = fmaf(C[ri], wr[1 * 8 + oc], a);                \
                    a = fmaf(P[ri], wr[2 * 8 + oc], a);                \
                    acc[ro][oc] = a;                                   \
                }                                                      \
            }                                                          \
        }                                                              \
    }

__global__ __launch_bounds__(256) void dyn_conv_pipe(
    const float* __restrict__ x,     // (B, 8, 256, 256)
    const float* __restrict__ kern,  // (B, 576) in [ic][kh][kw][oc] layout
    float* __restrict__ out)         // (B, 8, 256, 256)
{
    const int b  = blockIdx.y;
    const int h0 = blockIdx.x * RPB;
    const int w  = threadIdx.x;

    const float* xb = x + (size_t)b * 8 * HC;
    const float* Kb = kern + b * 576;
    float*       ob = out + (size_t)b * 8 * HC;

    float acc[RPB][8];
#pragma unroll
    for (int r = 0; r < RPB; ++r)
#pragma unroll
        for (int oc = 0; oc < 8; ++oc) acc[r][oc] = 0.f;

    float Am[RPB + 2], Ac[RPB + 2], Ap[RPB + 2];   // current-ic x rows
    float Bm[RPB + 2], Bc[RPB + 2], Bp[RPB + 2];   // next-ic x rows

    LOADIC(0, Am, Ac, Ap);                         // prologue: ic=0 in flight

#pragma unroll 1
    for (int icp = 0; icp < 4; ++icp) {
        const int ic0 = icp * 2;
        // issue ic0+1 loads BEFORE computing ic0 — they fly under the FMAs
        LOADIC(ic0 + 1, Bm, Bc, Bp);
        COMPUTEIC(ic0, Am, Ac, Ap);
        // issue ic0+2 loads (if any) before computing ic0+1
        if (ic0 + 2 < 8) {
            LOADIC(ic0 + 2, Am, Ac, Ap);
        }
        COMPUTEIC(ic0 + 1, Bm, Bc, Bp);
    }

    const int hw0 = h0 * WW + w;
#pragma unroll
    for (int oc = 0; oc < 8; ++oc) {
        float* orow = ob + oc * HC + hw0;
#pragma unroll
        for (int r = 0; r < RPB; ++r) orow[r * WW] = acc[r][oc];
    }
}

// ---------------------------------------------------------------------------
// Fallback: fused variant (weights computed into LDS) if ws is too small.
// ---------------------------------------------------------------------------
__global__ __launch_bounds__(256) void dyn_conv_fused(
    const float* __restrict__ x,
    const float* __restrict__ dw,
    const float* __restrict__ Wg,
    const float* __restrict__ bg,
    float* __restrict__ out)
{
    __shared__ float kl[576];
    const int b  = blockIdx.y;
    const int h0 = blockIdx.x * RPB;
    const int w  = threadIdx.x;

    for (int j = threadIdx.x; j < 576; j += 256) {
        const int ic   = j / 72;
        const int rem  = j % 72;
        const int kh   = rem / 24;
        const int rem2 = rem % 24;
        const int kw   = rem2 / 8;
        const int oc   = rem2 % 8;
        const int o    = ic * 9 + kh * 3 + kw;
        const float* d = dw + b * 64 + oc * 8;
        const float* g = Wg + o * 8;
        float v = bg[o];
#pragma unroll
        for (int i = 0; i < 8; ++i) v = fmaf(d[i], g[i], v);
        kl[j] = v;
    }
    __syncthreads();

    const float* xb = x + (size_t)b * 8 * HC;
    float*       ob = out + (size_t)b * 8 * HC;

    float acc[RPB][8];
#pragma unroll
    for (int r = 0; r < RPB; ++r)
#pragma unroll
        for (int oc = 0; oc < 8; ++oc) acc[r][oc] = 0.f;

#pragma unroll 1
    for (int ic = 0; ic < 8; ++ic) {
        const float* xch = xb + ic * HC;
#pragma unroll
        for (int ri = 0; ri < RPB + 2; ++ri) {
            const int row = h0 - 1 + ri;
            float xm = 0.f, xc = 0.f, xp = 0.f;
            if (row >= 0 && row < 256) {
                const float* xr = xch + row * WW;
                xc = xr[w];
                xm = (w > 0)   ? xr[w - 1] : 0.f;
                xp = (w < 255) ? xr[w + 1] : 0.f;
            }
#pragma unroll
            for (int kh = 0; kh < 3; ++kh) {
                const int ro = ri - kh;
                if (ro < 0 || ro >= RPB) continue;
                const float* wr = &kl[0] + ic * 72 + kh * 24;
#pragma unroll
                for (int oc = 0; oc < 8; ++oc) {
                    float a = acc[ro][oc];
                    a = fmaf(xm, wr[0 * 8 + oc], a);
                    a = fmaf(xc, wr[1 * 8 + oc], a);
                    a = fmaf(xp, wr[2 * 8 + oc], a);
                    acc[ro][oc] = a;
                }
            }
        }
    }

    const int hw0 = h0 * WW + w;
#pragma unroll
    for (int oc = 0; oc < 8; ++oc) {
        float* orow = ob + oc * HC + hw0;
#pragma unroll
        for (int r = 0; r < RPB; ++r) orow[r * WW] = acc[r][oc];
    }
}

extern "C" void kernel_launch(void* const* d_in, const int* in_sizes, int n_in,
                              void* d_out, int out_size, void* d_ws, size_t ws_size,
                              hipStream_t stream) {
    const float* x  = (const float*)d_in[0];  // (64,8,256,256)
    const float* dw = (const float*)d_in[1];  // (64,8,8)
    const float* Wg = (const float*)d_in[2];  // (72,8)
    const float* bg = (const float*)d_in[3];  // (72,)
    float* out = (float*)d_out;

    const dim3 grid(256 / RPB, 64);   // 64 row-tiles x 64 samples
    const dim3 block(256);

    if (ws_size >= (size_t)(64 * 576 * sizeof(float))) {
        float* kern = (float*)d_ws;
        gen_kernels<<<dim3(64), dim3(576), 0, stream>>>(dw, Wg, bg, kern);
        dyn_conv_pipe<<<grid, block, 0, stream>>>(x, kern, out);
    } else {
        dyn_conv_fused<<<grid, block, 0, stream>>>(x, dw, Wg, bg, out);
    }
}

// Round 8
// 242.251 us; speedup vs baseline: 1.0587x; 1.0587x over previous
//
#include <hip/hip_runtime.h>

// DynamicConv2d: B=64, C=8, H=W=256, OUT_C=8, K=3, IN_FEAT=8
// out[b,oc,h,w] = sum_{ic,kh,kw} x[b,ic,h+kh-1,w+kw-1] *
//                 ( dot(dw[b,oc,:], Wg[ic*9+kh*3+kw,:]) + bg[ic*9+kh*3+kw] )
//
// Session log (conv-dispatch times):
//   R0: RPB=8 thread-per-col, 68 VGPR, occ 25.8%            -> 90.6 us
//   R2-R5: tilings w/ __launch_bounds__(..,8): 32-VGPR cap  -> 101-300 us
//          (spills masqueraded as "write amplification", up to 686 MB)
//   R6: RPB=4, no min-waves: 40 VGPR, occ 52%, clean traffic -> 88 us
//       decomposition: 41 us VALU issue + 47 us stall
//   R7: 2-deep SW pipeline: stall 47->37 us BUT issue 41->62  -> 98.7 us
//       (macro-duplicated addressing/movs; source-level pipelining adds
//        more instructions than the latency it hides)
//   R8 (this): R6 memory pattern byte-identical; FMA core paired over
//       adjacent oc as float2 -> v_pk_fma_f32 (VOP3P). 2304 -> 1152 FMA
//       instrs/wave. Weight pairs are 64-bit SGPR pairs (1 sgpr read/instr).
//       Element-wise identical math (same summation order). If pk not
//       selected, degrades to 2x v_fma = exact R6 (downside-bounded).
//   Rules learned: (1) __launch_bounds__ 2nd arg is a VGPR budget; over-ask
//   => scratch traffic (tripwire: WRITE_SIZE must be 131072 KB exactly);
//   (2) plain stride-1 scalar stores are the minimal-write pattern;
//   (3) shuffle halos & macro pipelines cost more VALU than they save.

#define HC   65536   // H*W
#define WW   256
#define RPB  4       // output rows per block; input rows per ic = RPB+2 = 6

typedef float floatx2 __attribute__((ext_vector_type(2)));

// ---------------------------------------------------------------------------
// Kernel 1: materialize per-sample conv weights into d_ws with layout
//   kern[b][ic][kh][kw][oc]  (so conv reads 72 contiguous floats per (b,ic);
//   oc adjacent -> (oc,oc+1) float2 pairs are 8B-aligned for pk_fma)
// ---------------------------------------------------------------------------
__global__ __launch_bounds__(576) void gen_kernels(
    const float* __restrict__ dw,   // (B, 8, 8)
    const float* __restrict__ Wg,   // (72, 8)
    const float* __restrict__ bg,   // (72,)
    float* __restrict__ kern)       // (B, 576)
{
    const int b = blockIdx.x;
    const int j = threadIdx.x;
    if (j >= 576) return;
    const int ic   = j / 72;
    const int rem  = j % 72;
    const int kh   = rem / 24;
    const int rem2 = rem % 24;
    const int kw   = rem2 / 8;
    const int oc   = rem2 % 8;
    const int o    = ic * 9 + kh * 3 + kw;   // lin output index

    const float* d = dw + b * 64 + oc * 8;
    const float* g = Wg + o * 8;
    float v = bg[o];
#pragma unroll
    for (int i = 0; i < 8; ++i) v = fmaf(d[i], g[i], v);
    kern[b * 576 + j] = v;
}

// ---------------------------------------------------------------------------
// Kernel 2: the conv. One block = one sample b x one 4-row tile, 256
// threads = one thread per W column (stride-1 coalesced loads/stores —
// measured minimal traffic: FETCH 99 MB, WRITE 131072 KB exact).
// FMA core paired over oc: acc[r][p] holds (oc=2p, oc=2p+1); x-taps
// broadcast into both halves; weights read as float2 (64-bit sgpr pair).
// ---------------------------------------------------------------------------
__global__ __launch_bounds__(256) void dyn_conv_pk(
    const float* __restrict__ x,     // (B, 8, 256, 256)
    const float* __restrict__ kern,  // (B, 576) in [ic][kh][kw][oc] layout
    float* __restrict__ out)         // (B, 8, 256, 256)
{
    const int b  = blockIdx.y;
    const int h0 = blockIdx.x * RPB;
    const int w  = threadIdx.x;

    const float*   xb  = x + (size_t)b * 8 * HC;
    const floatx2* Kb2 = reinterpret_cast<const floatx2*>(kern + b * 576);
    float*         ob  = out + (size_t)b * 8 * HC;

    floatx2 acc[RPB][4];                 // [row][oc-pair] — 32 fp32 regs
#pragma unroll
    for (int r = 0; r < RPB; ++r)
#pragma unroll
        for (int p = 0; p < 4; ++p) acc[r][p] = (floatx2)(0.f);

#pragma unroll 1
    for (int ic = 0; ic < 8; ++ic) {
        // 36 wave-uniform float2 weights for this ic -> SGPR pairs
        floatx2 wk2[36];
        const floatx2* Kic2 = Kb2 + ic * 36;
#pragma unroll
        for (int t = 0; t < 36; ++t) wk2[t] = Kic2[t];

        const float* xch = xb + ic * HC;
#pragma unroll
        for (int ri = 0; ri < RPB + 2; ++ri) {
            const int row = h0 - 1 + ri;
            float xm = 0.f, xc = 0.f, xp = 0.f;
            if (row >= 0 && row < 256) {          // uniform per block
                const float* xr = xch + row * WW;
                xc = xr[w];
                xm = (w > 0)   ? xr[w - 1] : 0.f; // per-lane edge guard
                xp = (w < 255) ? xr[w + 1] : 0.f;
            }
            const floatx2 vm = {xm, xm};          // broadcast taps
            const floatx2 vc = {xc, xc};
            const floatx2 vp = {xp, xp};
            // input row (h0-1+ri) feeds output row ro = ri - kh
#pragma unroll
            for (int kh = 0; kh < 3; ++kh) {
                const int ro = ri - kh;
                if (ro < 0 || ro >= RPB) continue;  // compile-time pruned
                const floatx2* wr = &wk2[kh * 12];  // [kw][oc-pair]
#pragma unroll
                for (int p = 0; p < 4; ++p) {
                    floatx2 a = acc[ro][p];
                    a = __builtin_elementwise_fma(vm, wr[0 * 4 + p], a);
                    a = __builtin_elementwise_fma(vc, wr[1 * 4 + p], a);
                    a = __builtin_elementwise_fma(vp, wr[2 * 4 + p], a);
                    acc[ro][p] = a;
                }
            }
        }
    }

    // Stores: identical addresses/pattern to R6 (proven WRITE = 131072 KB).
    const int hw0 = h0 * WW + w;
#pragma unroll
    for (int p = 0; p < 4; ++p) {
        float* orow0 = ob + (2 * p)     * HC + hw0;
        float* orow1 = ob + (2 * p + 1) * HC + hw0;
#pragma unroll
        for (int r = 0; r < RPB; ++r) {
            orow0[r * WW] = acc[r][p].x;
            orow1[r * WW] = acc[r][p].y;
        }
    }
}

// ---------------------------------------------------------------------------
// Fallback: fused variant (weights computed into LDS) if ws is too small.
// ---------------------------------------------------------------------------
__global__ __launch_bounds__(256) void dyn_conv_fused(
    const float* __restrict__ x,
    const float* __restrict__ dw,
    const float* __restrict__ Wg,
    const float* __restrict__ bg,
    float* __restrict__ out)
{
    __shared__ float kl[576];
    const int b  = blockIdx.y;
    const int h0 = blockIdx.x * RPB;
    const int w  = threadIdx.x;

    for (int j = threadIdx.x; j < 576; j += 256) {
        const int ic   = j / 72;
        const int rem  = j % 72;
        const int kh   = rem / 24;
        const int rem2 = rem % 24;
        const int kw   = rem2 / 8;
        const int oc   = rem2 % 8;
        const int o    = ic * 9 + kh * 3 + kw;
        const float* d = dw + b * 64 + oc * 8;
        const float* g = Wg + o * 8;
        float v = bg[o];
#pragma unroll
        for (int i = 0; i < 8; ++i) v = fmaf(d[i], g[i], v);
        kl[j] = v;
    }
    __syncthreads();

    const float* xb = x + (size_t)b * 8 * HC;
    float*       ob = out + (size_t)b * 8 * HC;

    float acc[RPB][8];
#pragma unroll
    for (int r = 0; r < RPB; ++r)
#pragma unroll
        for (int oc = 0; oc < 8; ++oc) acc[r][oc] = 0.f;

#pragma unroll 1
    for (int ic = 0; ic < 8; ++ic) {
        const float* xch = xb + ic * HC;
#pragma unroll
        for (int ri = 0; ri < RPB + 2; ++ri) {
            const int row = h0 - 1 + ri;
            float xm = 0.f, xc = 0.f, xp = 0.f;
            if (row >= 0 && row < 256) {
                const float* xr = xch + row * WW;
                xc = xr[w];
                xm = (w > 0)   ? xr[w - 1] : 0.f;
                xp = (w < 255) ? xr[w + 1] : 0.f;
            }
#pragma unroll
            for (int kh = 0; kh < 3; ++kh) {
                const int ro = ri - kh;
                if (ro < 0 || ro >= RPB) continue;
                const float* wr = &kl[0] + ic * 72 + kh * 24;
#pragma unroll
                for (int oc = 0; oc < 8; ++oc) {
                    float a = acc[ro][oc];
                    a = fmaf(xm, wr[0 * 8 + oc], a);
                    a = fmaf(xc, wr[1 * 8 + oc], a);
                    a = fmaf(xp, wr[2 * 8 + oc], a);
                    acc[ro][oc] = a;
                }
            }
        }
    }

    const int hw0 = h0 * WW + w;
#pragma unroll
    for (int oc = 0; oc < 8; ++oc) {
        float* orow = ob + oc * HC + hw0;
#pragma unroll
        for (int r = 0; r < RPB; ++r) orow[r * WW] = acc[r][oc];
    }
}

extern "C" void kernel_launch(void* const* d_in, const int* in_sizes, int n_in,
                              void* d_out, int out_size, void* d_ws, size_t ws_size,
                              hipStream_t stream) {
    const float* x  = (const float*)d_in[0];  // (64,8,256,256)
    const float* dw = (const float*)d_in[1];  // (64,8,8)
    const float* Wg = (const float*)d_in[2];  // (72,8)
    const float* bg = (const float*)d_in[3];  // (72,)
    float* out = (float*)d_out;

    const dim3 grid(256 / RPB, 64);   // 64 row-tiles x 64 samples
    const dim3 block(256);

    if (ws_size >= (size_t)(64 * 576 * sizeof(float))) {
        float* kern = (float*)d_ws;
        gen_kernels<<<dim3(64), dim3(576), 0, stream>>>(dw, Wg, bg, kern);
        dyn_conv_pk<<<grid, block, 0, stream>>>(x, kern, out);
    } else {
        dyn_conv_fused<<<grid, block, 0, stream>>>(x, dw, Wg, bg, out);
    }
}